// Round 1
// 175.355 us; speedup vs baseline: 1.2602x; 1.2602x over previous
//
#include <hip/hip_runtime.h>
#include <hip/hip_bf16.h>

// out[b,o,hw] = sum_c W[o,c] * relu(x[b,c,hw]*scale[c] + shift[c])
// B=256, Cin=2112, Cout=192, HW=49, fp32 in HBM, bf16 MFMA internally.
//
// R8: FUSE bnpack+gemm into one kernel (one block per batch image b,
// 512 threads = 8 waves). Eliminates the 53 MB hpack round trip
// (bnpack wrote it at 21.6% BW; gemm re-read it) and one launch.
// Per K-step (32 channels): the x slab (6272 B, contiguous) is streamed
// into registers 3 steps ahead, BN+ReLU+bf16-transposed into a
// double-buffered LDS tile (bnpack's proven swizzle), and consumed by
// MFMA in the same kernel. Single raw s_barrier per step with explicit
// lgkmcnt(0) only -- no vmcnt drain, so the 3-deep x prefetch and
// 2-deep A prefetch stay in flight across barriers.
// Wave split: mg = wave&3 owns 48 Cout rows (3 M-tiles), ng = wave>>2
// owns 32 hw cols (2 N-tiles) -> A-fragments read 2x/block, L2-resident.

#define CIN    2112
#define COUT   192
#define HWS    49
#define BK     32
#define NSTEP  (CIN / BK)     // 66
#define EPSV   1e-5f
#define SLAB   (BK * HWS)     // 1568 elements per (b,ks) slab

typedef __bf16 bf16;
typedef __attribute__((ext_vector_type(8))) __bf16 bf16x8;
typedef __attribute__((ext_vector_type(4))) float  f32x4;

// ---------- kernel 1: W fp32 -> bf16 in A-fragment order (unchanged) ----------
__global__ __launch_bounds__(256)
void w_repack_kernel(const float* __restrict__ W, bf16* __restrict__ Wb) {
    const int t = blockIdx.x * 256 + threadIdx.x;       // 66*12*64 = 50688
    if (t >= NSTEP * 12 * 64) return;
    const int lane = t & 63;
    const int gmt  = (t >> 6) % 12;
    const int ks   = t / (12 * 64);
    const int row  = gmt * 16 + (lane & 15);
    const int k    = ks * BK + (lane >> 4) * 8;
    const float* src = W + (size_t)row * CIN + k;
    f32x4 a = *(const f32x4*)src;
    f32x4 c = *(const f32x4*)(src + 4);
    bf16x8 o;
    #pragma unroll
    for (int j = 0; j < 4; j++) { o[j] = (bf16)a[j]; o[j + 4] = (bf16)c[j]; }
    *(bf16x8*)(Wb + (size_t)t * 8) = o;
}

// ---------- kernel 2: fused BN+ReLU+transpose-pack+GEMM ----------
__global__ __launch_bounds__(512, 2)
void fused_kernel(const float* __restrict__ x,
                  const float* __restrict__ gamma,
                  const float* __restrict__ beta,
                  const float* __restrict__ rmean,
                  const float* __restrict__ rvar,
                  const bf16* __restrict__ Wb,
                  float* __restrict__ out)
{
    __shared__ float2 ss[CIN + 2];                   // BN scale/shift (+pad)
    __shared__ __align__(16) bf16 bt[2][SLAB];       // double-buffered B tile

    const int tid = threadIdx.x;
    const int b   = blockIdx.x;

    // BN params -> LDS
    for (int c = tid; c < CIN; c += 512) {
        float inv = rsqrtf(rvar[c] + EPSV);
        float s   = gamma[c] * inv;
        ss[c] = make_float2(s, beta[c] - rmean[c] * s);
    }
    if (tid < 2) ss[CIN + tid] = make_float2(0.f, 0.f);

    // ---- staging role: threads 0..391 each own 4 consecutive floats of the slab
    const bool act = tid < (SLAB / 4);               // 392
    const int fb  = tid * 4;
    const int cl0 = fb / HWS;                        // channel-in-slab 0..31
    const int hw0 = fb - cl0 * HWS;
    const int jw  = (hw0 + 4 <= HWS) ? 4 : (HWS - hw0);   // elems in channel cl0
    int addrs[4];
    #pragma unroll
    for (int j = 0; j < 4; j++) {
        int hw = hw0 + j, cl = cl0;
        if (hw >= HWS) { hw -= HWS; cl += 1; }
        const int rot = ((cl >> 3) + (hw >> 2)) & 3;      // bank swizzle
        addrs[j] = hw * BK + rot * 8 + (cl & 7);
    }
    const float* xs = x + (size_t)b * (CIN * HWS) + fb;

    // ---- compute role: 8 waves = 4 M-groups x 2 N-groups
    const int lane = tid & 63;
    const int wv   = tid >> 6;
    const int mg   = wv & 3;          // Cout rows mg*48 .. +48
    const int ng   = wv >> 2;         // hw cols  ng*32 .. +32
    const int l15  = lane & 15;
    const int q    = lane >> 4;

    const int hwc0 = ng * 32 + l15;               // <= 47, always valid
    int hwc1 = ng * 32 + 16 + l15;
    if (hwc1 > 48) hwc1 = 48;                     // dup col 48 (ng=1 tail)
    const int bad0 = hwc0 * BK + ((q + (hwc0 >> 2)) & 3) * 8;
    const int bad1 = hwc1 * BK + ((q + (hwc1 >> 2)) & 3) * 8;

    const bf16* apL = Wb + (size_t)(mg * 3) * 512 + (size_t)lane * 8;

    f32x4 acc[3][2];
    #pragma unroll
    for (int mt = 0; mt < 3; mt++) { acc[mt][0] = (f32x4)(0.f); acc[mt][1] = (f32x4)(0.f); }

    // prologue: 3-deep x prefetch, 2-deep A prefetch
    f32x4 xq[3];
    if (act) {
        xq[0] = *(const f32x4*)(xs);
        xq[1] = *(const f32x4*)(xs + SLAB);
        xq[2] = *(const f32x4*)(xs + 2 * SLAB);
    }
    bf16x8 ar[2][3];
    #pragma unroll
    for (int mt = 0; mt < 3; mt++) {
        ar[0][mt] = *(const bf16x8*)(apL + (size_t)(mt * 512));
        ar[1][mt] = *(const bf16x8*)(apL + (size_t)(6144 + mt * 512));
    }

    __syncthreads();   // ss ready (one-time full sync is fine)

    // stage step 0 into bt[0]
    if (act) {
        const float2 s0 = ss[cl0];
        const float2 s1 = ss[cl0 + 1];
        #pragma unroll
        for (int j = 0; j < 4; j++) {
            const float sc = (j >= jw) ? s1.x : s0.x;
            const float sh = (j >= jw) ? s1.y : s0.y;
            bt[0][addrs[j]] = (bf16)fmaxf(fmaf(xq[0][j], sc, sh), 0.f);
        }
    }
    asm volatile("s_waitcnt lgkmcnt(0)" ::: "memory");
    __builtin_amdgcn_s_barrier();

    // main loop: fully unrolled, ONE barrier per step.
    // step ks: read bt[ks&1]; write bt[(ks+1)&1]; barrier; MFMA.
    // (reads of buf k precede the barrier that precedes the next writes
    //  to buf k -> race-free with a single barrier.)
    #pragma unroll
    for (int ks = 0; ks < NSTEP; ks++) {
        const int p = ks & 1;
        const bf16x8 b0 = *(const bf16x8*)&bt[p][bad0];
        const bf16x8 b1 = *(const bf16x8*)&bt[p][bad1];

        if (ks < NSTEP - 1 && act) {               // transform slab ks+1
            const int cb = (ks + 1) * BK;
            const float2 s0 = ss[cb + cl0];
            const float2 s1 = ss[cb + cl0 + 1];
            const f32x4 v = xq[(ks + 1) % 3];      // static after unroll
            #pragma unroll
            for (int j = 0; j < 4; j++) {
                const float sc = (j >= jw) ? s1.x : s0.x;
                const float sh = (j >= jw) ? s1.y : s0.y;
                bt[p ^ 1][addrs[j]] = (bf16)fmaxf(fmaf(v[j], sc, sh), 0.f);
            }
        }
        if (ks < NSTEP - 3 && act)                 // x load 3 steps ahead
            xq[(ks + 3) % 3] = *(const f32x4*)(xs + (size_t)(ks + 3) * SLAB);

        asm volatile("s_waitcnt lgkmcnt(0)" ::: "memory");
        __builtin_amdgcn_s_barrier();

        #pragma unroll
        for (int mt = 0; mt < 3; mt++) {
            acc[mt][0] = __builtin_amdgcn_mfma_f32_16x16x32_bf16(ar[p][mt], b0, acc[mt][0], 0, 0, 0);
            acc[mt][1] = __builtin_amdgcn_mfma_f32_16x16x32_bf16(ar[p][mt], b1, acc[mt][1], 0, 0, 0);
        }
        if (ks < NSTEP - 2) {                      // A load 2 steps ahead
            #pragma unroll
            for (int mt = 0; mt < 3; mt++)
                ar[p][mt] = *(const bf16x8*)(apL + (size_t)(ks + 2) * 6144 + (size_t)(mt * 512));
        }
    }

    // epilogue: C/D layout col=l15 -> hw, row=q*4+r. Disjoint stores.
    float* ob = out + (size_t)b * (COUT * HWS);
    const int hw1 = ng * 32 + 16 + l15;            // unclamped for predicate
    #pragma unroll
    for (int mt = 0; mt < 3; mt++) {
        const int row0 = mg * 48 + mt * 16 + q * 4;
        #pragma unroll
        for (int r = 0; r < 4; r++)
            ob[(size_t)(row0 + r) * HWS + hwc0] = acc[mt][0][r];
        if (hw1 < HWS) {
            #pragma unroll
            for (int r = 0; r < 4; r++)
                ob[(size_t)(row0 + r) * HWS + hw1] = acc[mt][1][r];
        }
    }
}

extern "C" void kernel_launch(void* const* d_in, const int* in_sizes, int n_in,
                              void* d_out, int out_size, void* d_ws, size_t ws_size,
                              hipStream_t stream) {
    const float* x     = (const float*)d_in[0];
    const float* gamma = (const float*)d_in[1];
    const float* beta  = (const float*)d_in[2];
    const float* rmean = (const float*)d_in[3];
    const float* rvar  = (const float*)d_in[4];
    const float* W     = (const float*)d_in[5];
    float* out = (float*)d_out;

    bf16* Wb = (bf16*)d_ws;                        // 811,008 B, L2-resident

    w_repack_kernel<<<dim3(198), dim3(256), 0, stream>>>(W, Wb);
    fused_kernel<<<dim3(256), dim3(512), 0, stream>>>(
        x, gamma, beta, rmean, rvar, Wb, out);
}